// Round 4
// baseline (1075.732 us; speedup 1.0000x reference)
//
#include <hip/hip_runtime.h>
#include <math.h>

#define T_TOK 8192
#define D_DIM 1024
#define F_DIM 4096
#define E_NUM 8
#define BT    128                  // row tile; expert groups padded to this
#define CAP   (T_TOK + E_NUM*BT)   // 9216 max padded rows
#define NRT   (CAP/BT)             // 72 row tiles

typedef unsigned short ushort_t;
typedef __attribute__((ext_vector_type(8))) short bf16x8;   // 8 bf16 = 4 VGPR
typedef __attribute__((ext_vector_type(4))) float f32x4;
typedef __attribute__((ext_vector_type(4))) unsigned int u32x4;

// ---------------- workspace layout (bytes). Needs ~189 MiB of d_ws. ---------
#define ALIGN256(x) (((x) + (size_t)255) & ~(size_t)255)
constexpr size_t OFF_ASSIGN = 0;
constexpr size_t OFF_POS    = OFF_ASSIGN + (size_t)T_TOK*4;
constexpr size_t OFF_ALPHA  = OFF_POS    + (size_t)T_TOK*4;
constexpr size_t OFF_MU     = OFF_ALPHA  + (size_t)T_TOK*4;
constexpr size_t OFF_RSTD   = OFF_MU     + (size_t)T_TOK*4;
constexpr size_t OFF_COUNTS = OFF_RSTD   + (size_t)T_TOK*4;
constexpr size_t OFF_PADOFF = OFF_COUNTS + 64;
constexpr size_t OFF_PERM   = OFF_PADOFF + 64;
constexpr size_t OFF_XSH    = ALIGN256(OFF_PERM + (size_t)CAP*4);
constexpr size_t SZ_XS      = (size_t)CAP*D_DIM*2;
constexpr size_t OFF_XSL    = OFF_XSH + SZ_XS;
constexpr size_t SZ_H       = (size_t)CAP*F_DIM*2;
constexpr size_t OFF_HH     = ALIGN256(OFF_XSL + SZ_XS);
constexpr size_t OFF_HL     = OFF_HH + SZ_H;
constexpr size_t WS_NEED    = OFF_HL + SZ_H;   // ~189 MiB

// ---------------- bf16 helpers ----------------
__device__ __forceinline__ ushort_t f2bf(float v) {          // RNE
    unsigned u = __float_as_uint(v);
    unsigned r = u + 0x7FFF + ((u >> 16) & 1);
    return (ushort_t)(r >> 16);
}
__device__ __forceinline__ float bf2f(ushort_t h) {
    return __uint_as_float(((unsigned)h) << 16);
}
__device__ __forceinline__ unsigned rne_bits(unsigned u) {   // RNE, result in hi16
    return u + 0x7FFF + ((u >> 16) & 1);
}

__device__ __forceinline__ void gload_lds16(const void* g, void* l) {
    __builtin_amdgcn_global_load_lds(
        (const __attribute__((address_space(1))) unsigned int*)(const void*)g,
        (__attribute__((address_space(3))) unsigned int*)(void*)l, 16, 0, 0);
}

// ---------------- kernel 0: zero expert counters ----------------
__global__ void k_zero(int* counts) {
    if (threadIdx.x < 16) counts[threadIdx.x] = 0;
}

// ---------------- kernel 1: routing (affinity, argmax, alpha, LN stats) -----
__global__ __launch_bounds__(256) void k_route(
    const float* __restrict__ x, const float* __restrict__ cent,
    int* __restrict__ assign, int* __restrict__ pos,
    float* __restrict__ alpha, float* __restrict__ mu, float* __restrict__ rstd,
    int* __restrict__ counts)
{
    int t = blockIdx.x;
    const float* xt = x + (size_t)t * D_DIM;
    int tid = threadIdx.x;

    float a[E_NUM];
    #pragma unroll
    for (int e = 0; e < E_NUM; ++e) a[e] = 0.f;
    float s = 0.f, sq = 0.f;

    #pragma unroll
    for (int k = 0; k < D_DIM / 256; ++k) {
        int d = tid + 256 * k;
        float v = xt[d];
        s += v; sq += v * v;
        #pragma unroll
        for (int e = 0; e < E_NUM; ++e) a[e] = fmaf(v, cent[e * D_DIM + d], a[e]);
    }
    #pragma unroll
    for (int off = 32; off; off >>= 1) {
        #pragma unroll
        for (int e = 0; e < E_NUM; ++e) a[e] += __shfl_down(a[e], off, 64);
        s  += __shfl_down(s,  off, 64);
        sq += __shfl_down(sq, off, 64);
    }
    __shared__ float red[4][10];
    int wid = tid >> 6, lane = tid & 63;
    if (lane == 0) {
        #pragma unroll
        for (int e = 0; e < E_NUM; ++e) red[wid][e] = a[e];
        red[wid][8] = s; red[wid][9] = sq;
    }
    __syncthreads();
    if (tid == 0) {
        float af[E_NUM], ss, ssq;
        #pragma unroll
        for (int e = 0; e < E_NUM; ++e)
            af[e] = red[0][e] + red[1][e] + red[2][e] + red[3][e];
        ss  = red[0][8] + red[1][8] + red[2][8] + red[3][8];
        ssq = red[0][9] + red[1][9] + red[2][9] + red[3][9];
        int best = 0; float bv = af[0];
        #pragma unroll
        for (int e = 1; e < E_NUM; ++e) if (af[e] > bv) { bv = af[e]; best = e; }
        float m   = ss / (float)D_DIM;
        float var = ssq / (float)D_DIM - m * m;
        assign[t] = best;
        alpha[t]  = 1.f / (1.f + expf(-bv));
        mu[t]     = m;
        rstd[t]   = rsqrtf(var + 1e-5f);
        pos[t]    = atomicAdd(&counts[best], 1);
    }
}

// ---------------- kernel 2: padded prefix offsets ----------------
__global__ void k_padoff(const int* __restrict__ counts, int* __restrict__ padoff) {
    if (threadIdx.x == 0 && blockIdx.x == 0) {
        int off = 0;
        for (int e = 0; e < E_NUM; ++e) {
            padoff[e] = off;
            off += ((counts[e] + BT - 1) / BT) * BT;
        }
        padoff[E_NUM] = off;
    }
}

// ---------------- kernel 3: scatter + LN + bf16 hi/lo split ----------------
__global__ __launch_bounds__(256) void k_scatter(
    const float* __restrict__ x, const float* __restrict__ ln_g, const float* __restrict__ ln_b,
    const int* __restrict__ assign, const int* __restrict__ pos,
    const float* __restrict__ mu, const float* __restrict__ rstd,
    const int* __restrict__ padoff, int* __restrict__ perm,
    ushort_t* __restrict__ xsh, ushort_t* __restrict__ xsl)
{
    int t = blockIdx.x;
    int e = assign[t];
    int r = padoff[e] + pos[t];
    if (threadIdx.x == 0) perm[r] = t;
    float m = mu[t], rs = rstd[t];
    const float* xt = x + (size_t)t * D_DIM;
    const float* ge = ln_g + (size_t)e * D_DIM;
    const float* be = ln_b + (size_t)e * D_DIM;
    int d = threadIdx.x * 4;
    float4 xv = *(const float4*)(xt + d);
    float4 gv = *(const float4*)(ge + d);
    float4 bv = *(const float4*)(be + d);
    float v0 = fmaf((xv.x - m) * rs, gv.x, bv.x);
    float v1 = fmaf((xv.y - m) * rs, gv.y, bv.y);
    float v2 = fmaf((xv.z - m) * rs, gv.z, bv.z);
    float v3 = fmaf((xv.w - m) * rs, gv.w, bv.w);
    ushort4 hv, lv;
    hv.x = f2bf(v0); lv.x = f2bf(v0 - bf2f(hv.x));
    hv.y = f2bf(v1); lv.y = f2bf(v1 - bf2f(hv.y));
    hv.z = f2bf(v2); lv.z = f2bf(v2 - bf2f(hv.z));
    hv.w = f2bf(v3); lv.w = f2bf(v3 - bf2f(hv.w));
    *(ushort4*)(xsh + (size_t)r * D_DIM + d) = hv;
    *(ushort4*)(xsl + (size_t)r * D_DIM + d) = lv;
}

// ---------------- GEMM: bf16-split MFMA, 128x128 tile, BK=64 ---------------
// C[m][n] = sum_k A[m][k]*W[n][k].
// A staged as two bf16 planes (hi/lo), [128 rows][64 k], 8 slots/row of 16 B,
//   stored_slot = kgroup ^ (row&7), via pre-swizzled global source (m173).
// W staged as raw fp32 [128 rows][64 k] (32 KB), 16 slots/row of 16 B,
//   stored_slot = s ^ (row&7); split to bf16 hi/lo (RNE) in-register.
template<int KDIM, bool SECOND>
__global__ __launch_bounds__(256, 2) void k_gemm(
    const ushort_t* __restrict__ Ah, const ushort_t* __restrict__ Al,
    const float* __restrict__ W,            // fp32 [E][N][KDIM], N*KDIM = F*D
    const int* __restrict__ padoff, const int* __restrict__ counts,
    const float* __restrict__ bias,
    const int* __restrict__ perm, const float* __restrict__ alpha,
    const float* __restrict__ x, float* __restrict__ out,
    ushort_t* __restrict__ Hh, ushort_t* __restrict__ Hl)
{
    int r0 = blockIdx.x * BT;
    int total = padoff[E_NUM];
    if (r0 >= total) return;
    int e = 0;
    #pragma unroll
    for (int i = 1; i < E_NUM; ++i) if (r0 >= padoff[i]) e = i;

    const int tid = threadIdx.x;
    const int lane = tid & 63, wid = tid >> 6;
    const int l15 = lane & 15, lq = lane >> 4;
    // A staging lane map: 8-row chunks of 1024 B
    const int ra = lane >> 3;                 // row in chunk
    const int ga = (lane & 7) ^ ra;           // pre-swizzled k-group (16B units)
    // W staging lane map: 4-row chunks of 1024 B
    const int rw4 = lane >> 4;                // row in chunk (0..3)
    const int sw16 = lane & 15;               // dest slot
    const int gwe = sw16 ^ rw4;               // source slot, even chunk
    const int wr = (wid >> 1) * 64, wc = (wid & 1) * 64;
    const int c0 = blockIdx.y * 128;

    const ushort_t* aHp = Ah + (size_t)(r0 + ra) * KDIM + ga * 8;
    const ushort_t* aLp = Al + (size_t)(r0 + ra) * KDIM + ga * 8;
    const float* We = W + (size_t)e * F_DIM * D_DIM;

    __shared__ char smem[65536];   // 0: Ah(16K) 16384: Al(16K) 32768: Wf32(32K)

    f32x4 acc[4][4];
    #pragma unroll
    for (int i = 0; i < 4; ++i)
        #pragma unroll
        for (int j = 0; j < 4; ++j)
            #pragma unroll
            for (int q = 0; q < 4; ++q) acc[i][j][q] = 0.f;

    for (int kb = 0; kb < KDIM; kb += 64) {
        #pragma unroll
        for (int j = 0; j < 4; ++j) {            // A planes: 16 chunks each
            int cj = wid * 4 + j;
            size_t go = (size_t)cj * 8 * KDIM + kb;
            gload_lds16(aHp + go, smem + cj * 1024);
            gload_lds16(aLp + go, smem + 16384 + cj * 1024);
        }
        #pragma unroll
        for (int j = 0; j < 8; ++j) {            // W: 32 chunks
            int cj = wid * 8 + j;
            int rowl = cj * 4 + rw4;
            int g = (cj & 1) ? (gwe ^ 4) : gwe;  // == sw16 ^ (rowl&7)
            gload_lds16(We + (size_t)(c0 + rowl) * KDIM + kb + g * 4,
                        smem + 32768 + cj * 1024);
        }
        __syncthreads();
        #pragma unroll
        for (int ks = 0; ks < 2; ++ks) {
            const int g = ks * 4 + lq;
            bf16x8 ah[4], al[4];
            #pragma unroll
            for (int mr = 0; mr < 4; ++mr) {
                int row = wr + mr * 16 + l15;
                int sw = (g ^ (row & 7)) << 4;
                ah[mr] = *(const bf16x8*)(smem + row * 128 + sw);
                al[mr] = *(const bf16x8*)(smem + 16384 + row * 128 + sw);
            }
            #pragma unroll
            for (int nc = 0; nc < 4; ++nc) {
                int rww = wc + nc * 16 + l15;
                int s0 = (2 * g) ^ (rww & 7);
                int s1 = (2 * g + 1) ^ (rww & 7);
                const char* wrow = smem + 32768 + rww * 256;
                f32x4 w0 = *(const f32x4*)(wrow + s0 * 16);
                f32x4 w1 = *(const f32x4*)(wrow + s1 * 16);
                union { u32x4 u; bf16x8 h; } bh, bl;
                #pragma unroll
                for (int p = 0; p < 4; ++p) {
                    float v0 = (p < 2) ? w0[(p & 1) * 2]     : w1[(p & 1) * 2];
                    float v1 = (p < 2) ? w0[(p & 1) * 2 + 1] : w1[(p & 1) * 2 + 1];
                    unsigned h0 = rne_bits(__float_as_uint(v0));
                    unsigned h1 = rne_bits(__float_as_uint(v1));
                    bh.u[p] = __builtin_amdgcn_perm(h1, h0, 0x07060302);
                    float l0 = v0 - __uint_as_float(h0 & 0xFFFF0000u);
                    float l1 = v1 - __uint_as_float(h1 & 0xFFFF0000u);
                    unsigned q0 = rne_bits(__float_as_uint(l0));
                    unsigned q1 = rne_bits(__float_as_uint(l1));
                    bl.u[p] = __builtin_amdgcn_perm(q1, q0, 0x07060302);
                }
                #pragma unroll
                for (int mr = 0; mr < 4; ++mr) {
                    acc[mr][nc] = __builtin_amdgcn_mfma_f32_16x16x32_bf16(ah[mr], bh.h, acc[mr][nc], 0, 0, 0);
                    acc[mr][nc] = __builtin_amdgcn_mfma_f32_16x16x32_bf16(ah[mr], bl.h, acc[mr][nc], 0, 0, 0);
                    acc[mr][nc] = __builtin_amdgcn_mfma_f32_16x16x32_bf16(al[mr], bh.h, acc[mr][nc], 0, 0, 0);
                }
            }
        }
        __syncthreads();
    }

    // C/D layout (m89-verified): col = lane&15, row = (lane>>4)*4 + reg
    if constexpr (!SECOND) {
        const float* be = bias + (size_t)e * F_DIM;
        #pragma unroll
        for (int nc = 0; nc < 4; ++nc) {
            int col = c0 + wc + nc * 16 + l15;
            float bv = be[col];
            #pragma unroll
            for (int mr = 0; mr < 4; ++mr) {
                int rowb = r0 + wr + mr * 16 + lq * 4;
                #pragma unroll
                for (int rr = 0; rr < 4; ++rr) {
                    float v = acc[mr][nc][rr] + bv;
                    v = fmaxf(v, 0.f);
                    ushort_t h = f2bf(v);
                    ushort_t l = f2bf(v - bf2f(h));
                    size_t off = (size_t)(rowb + rr) * F_DIM + col;
                    Hh[off] = h; Hl[off] = l;
                }
            }
        }
    } else {
        int pbase = padoff[e], cnt = counts[e];
        const float* be = bias + (size_t)e * D_DIM;
        float bb[4];
        #pragma unroll
        for (int nc = 0; nc < 4; ++nc) bb[nc] = be[c0 + wc + nc * 16 + l15];
        #pragma unroll
        for (int mr = 0; mr < 4; ++mr) {
            #pragma unroll
            for (int rr = 0; rr < 4; ++rr) {
                int row = r0 + wr + mr * 16 + lq * 4 + rr;
                if (row - pbase < cnt) {
                    int t = perm[row];
                    float av = alpha[t];
                    const float* xr = x + (size_t)t * D_DIM;
                    float* outr = out + (size_t)t * D_DIM;
                    #pragma unroll
                    for (int nc = 0; nc < 4; ++nc) {
                        int col = c0 + wc + nc * 16 + l15;
                        outr[col] = fmaf(av, acc[mr][nc][rr] + bb[nc], xr[col]);
                    }
                }
            }
        }
    }
}

// ---------------- launcher ----------------
extern "C" void kernel_launch(void* const* d_in, const int* in_sizes, int n_in,
                              void* d_out, int out_size, void* d_ws, size_t ws_size,
                              hipStream_t stream) {
    const float* x    = (const float*)d_in[0];
    const float* cent = (const float*)d_in[1];
    const float* ln_g = (const float*)d_in[2];
    const float* ln_b = (const float*)d_in[3];
    const float* w1   = (const float*)d_in[4];
    const float* b1   = (const float*)d_in[5];
    const float* w2   = (const float*)d_in[6];
    const float* b2   = (const float*)d_in[7];
    float* out = (float*)d_out;
    char* ws = (char*)d_ws;
    (void)ws_size;   // requires ws_size >= WS_NEED (~189 MiB)

    int*      assign = (int*)     (ws + OFF_ASSIGN);
    int*      pos    = (int*)     (ws + OFF_POS);
    float*    alpha  = (float*)   (ws + OFF_ALPHA);
    float*    mu     = (float*)   (ws + OFF_MU);
    float*    rstd   = (float*)   (ws + OFF_RSTD);
    int*      counts = (int*)     (ws + OFF_COUNTS);
    int*      padoff = (int*)     (ws + OFF_PADOFF);
    int*      perm   = (int*)     (ws + OFF_PERM);
    ushort_t* xsh    = (ushort_t*)(ws + OFF_XSH);
    ushort_t* xsl    = (ushort_t*)(ws + OFF_XSL);
    ushort_t* Hh     = (ushort_t*)(ws + OFF_HH);
    ushort_t* Hl     = (ushort_t*)(ws + OFF_HL);

    k_zero<<<1, 64, 0, stream>>>(counts);
    k_route<<<T_TOK, 256, 0, stream>>>(x, cent, assign, pos, alpha, mu, rstd, counts);
    k_padoff<<<1, 1, 0, stream>>>(counts, padoff);
    k_scatter<<<T_TOK, 256, 0, stream>>>(x, ln_g, ln_b, assign, pos, mu, rstd,
                                         padoff, perm, xsh, xsl);
    k_gemm<D_DIM, false><<<dim3(NRT, F_DIM / 128), 256, 0, stream>>>(
        xsh, xsl, w1, padoff, counts, b1,
        nullptr, nullptr, nullptr, nullptr, Hh, Hl);
    k_gemm<F_DIM, true><<<dim3(NRT, D_DIM / 128), 256, 0, stream>>>(
        Hh, Hl, w2, padoff, counts, b2,
        perm, alpha, x, out, nullptr, nullptr);
}